// Round 2
// baseline (217.350 us; speedup 1.0000x reference)
//
#include <hip/hip_runtime.h>
#include <hip/hip_bf16.h>

// Problem constants
static constexpr int B_ = 64, A_ = 32, BOARD_ = 64, D_ = 5;
static constexpr long long FACN = (long long)B_ * A_ * BOARD_ * BOARD_ * D_; // 41,943,040
static constexpr long long CHN  = (long long)B_ * A_ * BOARD_ * BOARD_;      // 8,388,608
static constexpr int NAG = B_ * A_;                                          // 2048

// exp(-1/50), exp(-1/20)
static constexpr float FAC_DECAY = 0.9801986733067553f;
static constexpr float INH_DECAY = 0.9512294245007140f;

// Classify the element width of the `collisions` buffer (bool source; encoding
// could be int32/fp32 (4B), bf16/fp16 (2B), or byte (1B)).
// Reads exactly 2048 bytes = smallest possible encoding size -> always in bounds.
// Deterministic: same input -> same flag.
__global__ void sniff_kernel(const unsigned int* __restrict__ coll, int* __restrict__ flag) {
    if (blockIdx.x == 0 && threadIdx.x == 0) {
        bool w4 = true, h2 = true;
        for (int i = 0; i < 512; ++i) {
            unsigned int w = coll[i];
            if (!(w == 0u || w == 1u || w == 0x3F800000u)) w4 = false;
            unsigned int lo = w & 0xFFFFu, hi = w >> 16;
            bool lok = (lo == 0u || lo == 1u || lo == 0x3F80u || lo == 0x3C00u);
            bool hok = (hi == 0u || hi == 1u || hi == 0x3F80u || hi == 0x3C00u);
            if (!(lok && hok)) h2 = false;
        }
        *flag = w4 ? 4 : (h2 ? 2 : 1);
    }
}

// Bulk streaming decay over fp32: out[fac | inh | ch] = in * scale, float4 per iter.
__global__ __launch_bounds__(256) void bulk_kernel(
    const float4* __restrict__ fac_in, const float4* __restrict__ inh_in,
    const float4* __restrict__ ch_in, float4* __restrict__ out)
{
    const int FACV = (int)(FACN / 4);       // 10,485,760 vectors
    const int CHV  = (int)(CHN / 4);        //  2,097,152 vectors
    const int TOT  = 2 * FACV + CHV;        // 23,068,672 vectors
    int stride = gridDim.x * blockDim.x;
    for (int i = blockIdx.x * blockDim.x + threadIdx.x; i < TOT; i += stride) {
        const float4* src; int j; float s;
        if (i < FACV)            { src = fac_in; j = i;            s = FAC_DECAY; }
        else if (i < 2 * FACV)   { src = inh_in; j = i - FACV;     s = INH_DECAY; }
        else                     { src = ch_in;  j = i - 2 * FACV; s = 0.9f; }
        float4 v = src[j];
        v.x *= s; v.y *= s; v.z *= s; v.w *= s;
        out[i] = v; // output regions [fac|inh|ch] are contiguous in this order
    }
}

// Per-agent tail: the scatter index (b,a,y,x) is unique per (b,a) -> no atomics.
// Runs after bulk_kernel (stream-ordered); overwrites the scattered cells with
// decayed+added values computed from the ORIGINAL inputs, and writes safety.
__global__ __launch_bounds__(256) void agent_kernel(
    const float* __restrict__ pos, const float* __restrict__ goal,
    const float* __restrict__ spike,
    const float* __restrict__ fac_in, const float* __restrict__ inh_in,
    const float* __restrict__ ch_in,
    const void* __restrict__ coll, const int* __restrict__ flag,
    float* __restrict__ out)
{
    int idx = blockIdx.x * blockDim.x + threadIdx.x;
    if (idx >= NAG) return;

    float px = pos[idx * 2 + 0];
    float py = pos[idx * 2 + 1];
    int x = min(BOARD_ - 1, max(0, (int)px));   // trunc like .astype(int32); pos >= 0
    int y = min(BOARD_ - 1, max(0, (int)py));
    long long cell = ((long long)idx * BOARD_ + y) * BOARD_ + x;

    int f = *flag;
    bool c;
    if (f == 4)      c = ((const unsigned int*)coll)[idx] != 0u;
    else if (f == 2) c = ((const unsigned short*)coll)[idx] != 0u;
    else             c = ((const unsigned char*)coll)[idx] != 0u;

    // collision history cell + safety
    float chv = ch_in[cell] * 0.9f + (c ? 0.1f : 0.0f);
    const long long CHOFF  = 2 * FACN;
    const long long SAFOFF = CHOFF + CHN;
    out[CHOFF + cell] = chv;
    float safety = 1.0f - fminf(fmaxf(chv, 0.0f), 1.0f);
    out[SAFOFF + idx] = safety;
    bool safe = safety > 0.7f;

    // goal alignment, closed form per direction d: gn . delta[d] mapped to [0,1]
    float gx = goal[idx * 2 + 0] - px;
    float gy = goal[idx * 2 + 1] - py;
    float n = sqrtf(gx * gx + gy * gy) + 1e-8f;
    float gnx = gx / n, gny = gy / n;
    float align[5];
    align[0] = 0.5f;
    align[1] = (gnx + 1.0f) * 0.5f;
    align[2] = (gny + 1.0f) * 0.5f;
    align[3] = (1.0f - gnx) * 0.5f;
    align[4] = (1.0f - gny) * 0.5f;

    long long cd = cell * D_;
#pragma unroll
    for (int d = 0; d < D_; ++d) {
        bool sp = spike[idx * D_ + d] > 0.5f;
        bool fc = sp && safe && (align[d] > 0.6f);
        bool ic = sp && (!safe || (align[d] <= 0.4f));
        float fv = fac_in[cd + d] * FAC_DECAY + (fc ? 0.0002f : 0.0f);
        float iv = inh_in[cd + d] * INH_DECAY + (ic ? 0.0001f : 0.0f);
        out[cd + d] = fv;
        out[FACN + cd + d] = iv;
    }
}

extern "C" void kernel_launch(void* const* d_in, const int* in_sizes, int n_in,
                              void* d_out, int out_size, void* d_ws, size_t ws_size,
                              hipStream_t stream) {
    const float* pos   = (const float*)d_in[0];
    const float* goal  = (const float*)d_in[1];
    const float* spike = (const float*)d_in[2];
    const float* fac   = (const float*)d_in[3];
    const float* inh   = (const float*)d_in[4];
    const float* ch    = (const float*)d_in[5];
    const void*  coll  = d_in[6];
    float* out = (float*)d_out;
    int* flag = (int*)d_ws;

    hipLaunchKernelGGL(sniff_kernel, dim3(1), dim3(64), 0, stream,
                       (const unsigned int*)coll, flag);
    hipLaunchKernelGGL(bulk_kernel, dim3(2048), dim3(256), 0, stream,
                       (const float4*)fac, (const float4*)inh, (const float4*)ch, (float4*)out);
    hipLaunchKernelGGL(agent_kernel, dim3((NAG + 255) / 256), dim3(256), 0, stream,
                       pos, goal, spike, fac, inh, ch, coll, flag, out);
}

// Round 4
// 147.120 us; speedup vs baseline: 1.4774x; 1.4774x over previous
//
#include <hip/hip_runtime.h>

// Problem constants
static constexpr int B_ = 64, A_ = 32, BOARD_ = 64, D_ = 5;
static constexpr long long FACN = (long long)B_ * A_ * BOARD_ * BOARD_ * D_; // 41,943,040
static constexpr long long CHN  = (long long)B_ * A_ * BOARD_ * BOARD_;      // 8,388,608
static constexpr int NAG = B_ * A_;                                          // 2048

// exp(-1/50), exp(-1/20)
static constexpr float FAC_DECAY = 0.9801986733067553f;
static constexpr float INH_DECAY = 0.9512294245007140f;

// Native clang vector type — required by __builtin_nontemporal_load/store
// (HIP's float4 is a struct and is rejected).
typedef float f32x4 __attribute__((ext_vector_type(4)));

// Bulk streaming decay over fp32: out[fac | inh | ch] = in * scale.
// Grid-stride f32x4, unrolled x2 for MLP, nontemporal (pure streaming, no reuse).
__global__ __launch_bounds__(256) void bulk_kernel(
    const f32x4* __restrict__ fac_in, const f32x4* __restrict__ inh_in,
    const f32x4* __restrict__ ch_in, f32x4* __restrict__ out)
{
    const int FACV = (int)(FACN / 4);       // 10,485,760 vectors
    const int CHV  = (int)(CHN / 4);        //  2,097,152 vectors
    const int TOT  = 2 * FACV + CHV;        // 23,068,672 vectors (= 44 * 524288)
    const int S = gridDim.x * blockDim.x;   // 524,288 threads

    auto pick = [&](int i, const f32x4*& src, int& j, float& s) {
        if (i < FACV)          { src = fac_in; j = i;            s = FAC_DECAY; }
        else if (i < 2 * FACV) { src = inh_in; j = i - FACV;     s = INH_DECAY; }
        else                   { src = ch_in;  j = i - 2 * FACV; s = 0.9f; }
    };

    int i = blockIdx.x * blockDim.x + threadIdx.x;
    for (; i + S < TOT; i += 2 * S) {
        const f32x4 *p0, *p1; int j0, j1; float c0, c1;
        pick(i,     p0, j0, c0);
        pick(i + S, p1, j1, c1);
        f32x4 a = __builtin_nontemporal_load(&p0[j0]);
        f32x4 b = __builtin_nontemporal_load(&p1[j1]);
        a *= c0;
        b *= c1;
        __builtin_nontemporal_store(a, &out[i]);
        __builtin_nontemporal_store(b, &out[i + S]);
    }
    if (i < TOT) {  // tail (unused at 2048x256 with TOT = 44*S, kept for safety)
        const f32x4* p0; int j0; float c0;
        pick(i, p0, j0, c0);
        f32x4 a = __builtin_nontemporal_load(&p0[j0]);
        a *= c0;
        __builtin_nontemporal_store(a, &out[i]);
    }
}

// Per-agent tail: the scatter index (b,a,y,x) is unique per (b,a) -> no atomics.
// Runs after bulk_kernel (stream-ordered); overwrites the scattered cells with
// decayed+added values computed from the ORIGINAL inputs, and writes safety.
// The collisions-dtype sniff is done per-block in parallel (reads 2048 bytes =
// smallest possible encoding of the 2048-entry bool buffer -> always in bounds).
__global__ __launch_bounds__(256) void agent_kernel(
    const float* __restrict__ pos, const float* __restrict__ goal,
    const float* __restrict__ spike,
    const float* __restrict__ fac_in, const float* __restrict__ inh_in,
    const float* __restrict__ ch_in,
    const void* __restrict__ coll,
    float* __restrict__ out)
{
    // ---- parallel dtype sniff (benign-race shared flags) ----
    __shared__ int s_w4, s_h2;
    if (threadIdx.x == 0) { s_w4 = 1; s_h2 = 1; }
    __syncthreads();
    {
        const unsigned int* cw = (const unsigned int*)coll;
        for (int k = threadIdx.x; k < 512; k += 256) {
            unsigned int w = cw[k];
            if (!(w == 0u || w == 1u || w == 0x3F800000u)) s_w4 = 0;
            unsigned int lo = w & 0xFFFFu, hi = w >> 16;
            if (!((lo == 0u || lo == 1u || lo == 0x3F80u || lo == 0x3C00u) &&
                  (hi == 0u || hi == 1u || hi == 0x3F80u || hi == 0x3C00u)))
                s_h2 = 0;
        }
    }
    __syncthreads();
    const int f = s_w4 ? 4 : (s_h2 ? 2 : 1);

    int idx = blockIdx.x * blockDim.x + threadIdx.x;
    if (idx >= NAG) return;

    float px = pos[idx * 2 + 0];
    float py = pos[idx * 2 + 1];
    int x = min(BOARD_ - 1, max(0, (int)px));   // trunc like .astype(int32); pos >= 0
    int y = min(BOARD_ - 1, max(0, (int)py));
    long long cell = ((long long)idx * BOARD_ + y) * BOARD_ + x;

    bool c;
    if (f == 4)      c = ((const unsigned int*)coll)[idx] != 0u;
    else if (f == 2) c = ((const unsigned short*)coll)[idx] != 0u;
    else             c = ((const unsigned char*)coll)[idx] != 0u;

    // collision history cell + safety
    float chv = ch_in[cell] * 0.9f + (c ? 0.1f : 0.0f);
    const long long CHOFF  = 2 * FACN;
    const long long SAFOFF = CHOFF + CHN;
    out[CHOFF + cell] = chv;
    float safety = 1.0f - fminf(fmaxf(chv, 0.0f), 1.0f);
    out[SAFOFF + idx] = safety;
    bool safe = safety > 0.7f;

    // goal alignment, closed form per direction d: (gn . delta[d] + 1) / 2
    float gx = goal[idx * 2 + 0] - px;
    float gy = goal[idx * 2 + 1] - py;
    float n = sqrtf(gx * gx + gy * gy) + 1e-8f;
    float gnx = gx / n, gny = gy / n;
    float align[5];
    align[0] = 0.5f;
    align[1] = (gnx + 1.0f) * 0.5f;
    align[2] = (gny + 1.0f) * 0.5f;
    align[3] = (1.0f - gnx) * 0.5f;
    align[4] = (1.0f - gny) * 0.5f;

    long long cd = cell * D_;
#pragma unroll
    for (int d = 0; d < D_; ++d) {
        bool sp = spike[idx * D_ + d] > 0.5f;
        bool fc = sp && safe && (align[d] > 0.6f);
        bool ic = sp && (!safe || (align[d] <= 0.4f));
        float fv = fac_in[cd + d] * FAC_DECAY + (fc ? 0.0002f : 0.0f);
        float iv = inh_in[cd + d] * INH_DECAY + (ic ? 0.0001f : 0.0f);
        out[cd + d] = fv;
        out[FACN + cd + d] = iv;
    }
}

extern "C" void kernel_launch(void* const* d_in, const int* in_sizes, int n_in,
                              void* d_out, int out_size, void* d_ws, size_t ws_size,
                              hipStream_t stream) {
    const float* pos   = (const float*)d_in[0];
    const float* goal  = (const float*)d_in[1];
    const float* spike = (const float*)d_in[2];
    const float* fac   = (const float*)d_in[3];
    const float* inh   = (const float*)d_in[4];
    const float* ch    = (const float*)d_in[5];
    const void*  coll  = d_in[6];
    float* out = (float*)d_out;

    hipLaunchKernelGGL(bulk_kernel, dim3(2048), dim3(256), 0, stream,
                       (const f32x4*)fac, (const f32x4*)inh, (const f32x4*)ch, (f32x4*)out);
    hipLaunchKernelGGL(agent_kernel, dim3((NAG + 255) / 256), dim3(256), 0, stream,
                       pos, goal, spike, fac, inh, ch, coll, out);
}